// Round 1
// baseline (692.222 us; speedup 1.0000x reference)
//
#include <hip/hip_runtime.h>
#include <math.h>

#define B_TOT   16384
#define SB      5
#define TPB     512
#define SSTRIDE 2540          // %32 == 12: post1 AGG reads at most 2-way bank-aliased (free)
#define OFF_H   0             // 11*36 = 396
#define OFF_EA  396           // 68
#define OFF_M   464           // 17*36 = 612
#define OFF_H1  OFF_M         // aliased: H1 live only between post1 and conv_T2; M dead there
#define OFF_AGG 1076          // 11*132 = 1452
#define OFF_TD  OFF_AGG       // TD/TS alias AGG region (792 <= 1452)
#define OFF_TS  (OFF_AGG + 396)
#define OFF_PACC (SB*SSTRIDE)         // 16 floats
#define OFF_PP   (SB*SSTRIDE + 16)    // 8 waves * 55 tasks = 440 floats
#define LDS_FLOATS (SB*SSTRIDE + 16 + 440)
#define AVG_LOG 0.9976091242438673f

// workspace layout (floats): [0..63] gacc/zero pad; folded post-weights after.
// W1eff index: ((i*3 + c)*8 + fq)*512 + j*4 + k   (fq = f/4, k = f&3)
//   -> per (class, wave) a contiguous 2KB stream, imm-offset addressable.
#define WS_W1    64
#define WS_W1_SZ (3*3*8*512)          // 36864
#define WS_W2    (WS_W1 + WS_W1_SZ)
#define WS_W2_SZ (3*3*128)            // 1152

__constant__ int   C_ESRC[17] = {0,0,1,1,2,0,3,4,5,6,7,2,8,3,6,9,1};
__constant__ int   C_EDST[17] = {3,4,3,5,5,6,6,7,7,8,8,9,9,10,10,10,10};
__constant__ int   C_INS[12]  = {0,0,0,0,2,3,5,7,9,11,13,17};
__constant__ int   C_INE[17]  = {0,2,1,3,4,5,6,7,8,9,10,11,12,13,14,15,16};
__constant__ float C_CNTC[11] = {1.f,1.f,1.f,2.f,1.f,2.f,2.f,2.f,2.f,2.f,4.f};
__constant__ int   C_CLS[11]  = {0,0,0,1,0,1,1,1,1,1,2};   // degree-class per node (cnt 1/2/4)

// ---- fold amp/att scalers into per-degree-class post-MLP weights (runs once per launch)
extern "C" __global__ void pna_fold(const float* __restrict__ W_post1,
                                    const float* __restrict__ W_post2,
                                    float* __restrict__ ws)
{
    const int t0 = blockIdx.x * blockDim.x + threadIdx.x;
    const int NT = gridDim.x * blockDim.x;
    if (t0 < 64) ws[t0] = 0.f;                      // gacc zero
    for (int idx = t0; idx < WS_W1_SZ; idx += NT) {
        const int k  = idx & 3;
        const int j  = (idx >> 2) & 127;
        const int fq = (idx >> 9) & 7;
        const int ic = idx >> 12;                   // 0..8
        const int c  = ic % 3, i = ic / 3;
        const float cn = (c == 0) ? 1.f : (c == 1) ? 2.f : 4.f;
        const float logd = log1pf(cn);
        const float amp = logd / AVG_LOG;
        const float att = AVG_LOG / logd;
        const int f = fq * 4 + k;
        const float* W = W_post1 + i * 384 * 32;
        ws[WS_W1 + idx] = W[j * 32 + f] + amp * W[(128 + j) * 32 + f] + att * W[(256 + j) * 32 + f];
    }
    for (int idx = t0; idx < WS_W2_SZ; idx += NT) {
        const int j  = idx & 127;
        const int ic = idx >> 7;
        const int c  = ic % 3, i = ic / 3;
        const float cn = (c == 0) ? 1.f : (c == 1) ? 2.f : 4.f;
        const float logd = log1pf(cn);
        const float amp = logd / AVG_LOG;
        const float att = AVG_LOG / logd;
        const float* W = W_post2 + i * 384;
        ws[WS_W2 + idx] = W[j] + amp * W[128 + j] + att * W[256 + j];
    }
}

// ---- per-node transform: T[n][f-octet] = H[n] @ Wpre[ty-part] (+bias for dst part)
// wave map: ty = w&1 (0: rows 0..31 +bias, 1: rows 32..63), f0 = (w>>1)*8
static __device__ __forceinline__ void conv_T(float* lds, int nsamp, int w, int lane, int hoff,
                                              const float* __restrict__ Wp,
                                              const float* __restrict__ bp)
{
    const int ty = w & 1;
    const int f0 = (w >> 1) * 8;
    const bool act = lane < nsamp * 11;
    const int cidx = act ? lane : 0;
    const int s = cidx / 11, n = cidx % 11;
    const float* Hrow = lds + s * SSTRIDE + hoff + n * 36;
    const float* wbase = Wp + ty * 32 * 32 + f0;        // wave-uniform -> s_load
    float acc[8];
#pragma unroll
    for (int f = 0; f < 8; f++) acc[f] = ty ? 0.f : bp[f0 + f];
#pragma unroll
    for (int kq = 0; kq < 8; kq++) {
        float4 a = *(const float4*)(Hrow + kq * 4);
#pragma unroll
        for (int kk = 0; kk < 4; kk++) {
            float av = (kk == 0) ? a.x : (kk == 1) ? a.y : (kk == 2) ? a.z : a.w;
            const float* wr = wbase + (kq * 4 + kk) * 32;
#pragma unroll
            for (int f = 0; f < 8; f++) acc[f] = fmaf(av, wr[f], acc[f]);
        }
    }
    float* T = lds + s * SSTRIDE + (ty ? OFF_TS : OFF_TD) + n * 36 + f0;
    if (act) {
        *(float4*)(T + 0) = make_float4(acc[0], acc[1], acc[2], acc[3]);
        *(float4*)(T + 4) = make_float4(acc[4], acc[5], acc[6], acc[7]);
    }
}

// ---- combine: m[e][f-octet] = relu(Td[dst] + Ts[src] + ea @ Wpre[64:68])
// wave map: f0 = (w&3)*8, v = w>>2; idx = v*64+lane over nsamp*17 (<=85)
static __device__ __forceinline__ void conv_combine(float* lds, int nsamp, int w, int lane,
                                                    const float* __restrict__ Wp)
{
    const int f0 = (w & 3) * 8, v = w >> 2;
    const int idx = v * 64 + lane;
    const bool act = idx < nsamp * 17;
    const int cidx = act ? idx : 0;
    const int s = cidx / 17, e = cidx % 17;
    float* S = lds + s * SSTRIDE;
    const int nd = C_EDST[e], ns = C_ESRC[e];
    float4 ev = *(const float4*)(S + OFF_EA + e * 4);
    const float* TD = S + OFF_TD + nd * 36 + f0;
    const float* TS = S + OFF_TS + ns * 36 + f0;
    float acc[8];
#pragma unroll
    for (int fq = 0; fq < 2; fq++) {
        float4 td = *(const float4*)(TD + fq * 4);
        float4 ts = *(const float4*)(TS + fq * 4);
        acc[fq*4+0] = td.x + ts.x; acc[fq*4+1] = td.y + ts.y;
        acc[fq*4+2] = td.z + ts.z; acc[fq*4+3] = td.w + ts.w;
    }
    const float* w64 = Wp + 64 * 32 + f0;   // wave-uniform rows
    const float* w65 = Wp + 65 * 32 + f0;
    const float* w66 = Wp + 66 * 32 + f0;
    const float* w67 = Wp + 67 * 32 + f0;
#pragma unroll
    for (int f = 0; f < 8; f++) {
        float a = acc[f];
        a = fmaf(ev.x, w64[f], a);
        a = fmaf(ev.y, w65[f], a);
        a = fmaf(ev.z, w66[f], a);
        a = fmaf(ev.w, w67[f], a);
        acc[f] = fmaxf(a, 0.f);
    }
    float* M = S + OFF_M + e * 36 + f0;
    if (act) {
        *(float4*)(M + 0) = make_float4(acc[0], acc[1], acc[2], acc[3]);
        *(float4*)(M + 4) = make_float4(acc[4], acc[5], acc[6], acc[7]);
    }
}

// ---- PNA aggregation into agg[n][128] = [mean | mn | mx | std]
static __device__ __forceinline__ void agg_phase(float* lds, int nsamp, int tid)
{
    for (int t = tid; t < nsamp * 88; t += TPB) {
        const int s = t / 88, r = t % 88, n = r >> 3, f = (r & 7) * 4;
        float* S = lds + s * SSTRIDE;
        const int e0 = C_INS[n], e1 = C_INS[n + 1];
        float4 sum = make_float4(0.f,0.f,0.f,0.f), sq = make_float4(0.f,0.f,0.f,0.f);
        float4 mn = make_float4(1e30f,1e30f,1e30f,1e30f), mx = make_float4(-1e30f,-1e30f,-1e30f,-1e30f);
        for (int t2 = e0; t2 < e1; t2++) {
            const int e = C_INE[t2];
            float4 mv = *(const float4*)(S + OFF_M + e * 36 + f);
            sum.x += mv.x; sum.y += mv.y; sum.z += mv.z; sum.w += mv.w;
            sq.x = fmaf(mv.x, mv.x, sq.x); sq.y = fmaf(mv.y, mv.y, sq.y);
            sq.z = fmaf(mv.z, mv.z, sq.z); sq.w = fmaf(mv.w, mv.w, sq.w);
            mn.x = fminf(mn.x, mv.x); mn.y = fminf(mn.y, mv.y); mn.z = fminf(mn.z, mv.z); mn.w = fminf(mn.w, mv.w);
            mx.x = fmaxf(mx.x, mv.x); mx.y = fmaxf(mx.y, mv.y); mx.z = fmaxf(mx.z, mv.z); mx.w = fmaxf(mx.w, mv.w);
        }
        const float inv = 1.f / C_CNTC[n];
        float4 mean = make_float4(sum.x*inv, sum.y*inv, sum.z*inv, sum.w*inv);
        float4 msq  = make_float4(sq.x*inv,  sq.y*inv,  sq.z*inv,  sq.w*inv);
        float4 sd;
        sd.x = sqrtf(fmaxf(msq.x - mean.x*mean.x, 0.f) + 1e-5f);
        sd.y = sqrtf(fmaxf(msq.y - mean.y*mean.y, 0.f) + 1e-5f);
        sd.z = sqrtf(fmaxf(msq.z - mean.z*mean.z, 0.f) + 1e-5f);
        sd.w = sqrtf(fmaxf(msq.w - mean.w*mean.w, 0.f) + 1e-5f);
        if (e0 == e1) { mn = make_float4(0.f,0.f,0.f,0.f); mx = make_float4(0.f,0.f,0.f,0.f); }
        float* A = S + OFF_AGG + n * 132;
        *(float4*)(A + 0  + f) = mean;
        *(float4*)(A + 32 + f) = mn;
        *(float4*)(A + 64 + f) = mx;
        *(float4*)(A + 96 + f) = sd;
    }
}

// ---- post1 (folded): h1[n][f-quad] = relu(AGG @ Weff[cls(n)] + b); wave: f0 = w*4
// Weff laid out so the wave's 128 j-steps are a contiguous 2KB stream per class.
static __device__ __forceinline__ void post1_phase(float* lds, int nsamp, int w, int lane,
                                                   const float* __restrict__ Wi,
                                                   const float* __restrict__ bp)
{
    const int f0 = w * 4;
    const bool act = lane < nsamp * 11;
    const int cidx = act ? lane : 0;
    const int s = cidx / 11, n = cidx % 11;
    const float* A  = lds + s * SSTRIDE + OFF_AGG + n * 132;
    const float* W0 = Wi + (C_CLS[n] * 8 + w) * 512;    // 3 distinct 2KB streams per wave
    float u0 = 0.f, u1 = 0.f, u2 = 0.f, u3 = 0.f;
#pragma unroll 4
    for (int jq = 0; jq < 32; jq++) {
        float4 a4 = *(const float4*)(A + jq * 4);
        const float* wb = W0 + jq * 16;
        float4 w0 = *(const float4*)(wb + 0);
        float4 w1 = *(const float4*)(wb + 4);
        float4 w2 = *(const float4*)(wb + 8);
        float4 w3 = *(const float4*)(wb + 12);
        u0 = fmaf(a4.x, w0.x, u0); u1 = fmaf(a4.x, w0.y, u1); u2 = fmaf(a4.x, w0.z, u2); u3 = fmaf(a4.x, w0.w, u3);
        u0 = fmaf(a4.y, w1.x, u0); u1 = fmaf(a4.y, w1.y, u1); u2 = fmaf(a4.y, w1.z, u2); u3 = fmaf(a4.y, w1.w, u3);
        u0 = fmaf(a4.z, w2.x, u0); u1 = fmaf(a4.z, w2.y, u1); u2 = fmaf(a4.z, w2.z, u2); u3 = fmaf(a4.z, w2.w, u3);
        u0 = fmaf(a4.w, w3.x, u0); u1 = fmaf(a4.w, w3.y, u1); u2 = fmaf(a4.w, w3.z, u2); u3 = fmaf(a4.w, w3.w, u3);
    }
    if (act) {
        float4 o;
        o.x = fmaxf(u0 + bp[f0 + 0], 0.f);
        o.y = fmaxf(u1 + bp[f0 + 1], 0.f);
        o.z = fmaxf(u2 + bp[f0 + 2], 0.f);
        o.w = fmaxf(u3 + bp[f0 + 3], 0.f);
        *(float4*)(lds + s * SSTRIDE + OFF_H1 + n * 36 + f0) = o;
    }
}

// ---- post2 part A (folded): per-wave j-split partials; wave handles j0 = w*16
static __device__ __forceinline__ void post2_partial(float* lds, int nsamp, int w, int lane,
                                                     const float* __restrict__ W2e)
{
    const int j0 = w * 16;
    const bool act = lane < nsamp * 11;
    const int cidx = act ? lane : 0;
    const int s = cidx / 11, n = cidx % 11;
    const float* A  = lds + s * SSTRIDE + OFF_AGG + n * 132 + j0;
    const float* Wn = W2e + C_CLS[n] * 128 + j0;
    float u = 0.f;
#pragma unroll
    for (int jq = 0; jq < 4; jq++) {
        float4 a4 = *(const float4*)(A + jq * 4);
        float4 wv = *(const float4*)(Wn + jq * 4);
        u = fmaf(a4.x, wv.x, u);
        u = fmaf(a4.y, wv.y, u);
        u = fmaf(a4.z, wv.z, u);
        u = fmaf(a4.w, wv.w, u);
    }
    if (act) lds[OFF_PP + w * 55 + lane] = u;
}

extern "C" __global__ void __launch_bounds__(TPB, 6)
pna_main(const float* __restrict__ x_input, const float* __restrict__ edge_attr,
         const float* __restrict__ W_emb,  const float* __restrict__ b_emb,
         const float* __restrict__ W_pre1, const float* __restrict__ b_pre1,
         const float* __restrict__ W1eff,  const float* __restrict__ b_post1,
         const float* __restrict__ W_pre2, const float* __restrict__ b_pre2,
         const float* __restrict__ W2eff,  const float* __restrict__ b_post2,
         float* __restrict__ gacc)
{
    extern __shared__ float lds[];
    const int tid = threadIdx.x;
    const int w = __builtin_amdgcn_readfirstlane(tid >> 6);   // wave id, uniform, 0..7
    const int lane = tid & 63;
    const int s0 = blockIdx.x * SB;
    const int nsamp = min(SB, B_TOT - s0);

    // stage edge_attr
    for (int t = tid; t < nsamp * 68; t += TPB)
        lds[(t / 68) * SSTRIDE + OFF_EA + (t % 68)] = edge_attr[(size_t)s0 * 68 + t];

    // embed directly from global x (L1-broadcast reads): H[n][f] = relu(X[n] @ W_emb[n] + b)
    for (int t = tid; t < nsamp * 352; t += TPB) {
        const int s = t / 352, r = t % 352, n = r >> 5, f = r & 31;
        const float* Xs = x_input + (size_t)(s0 + s) * 44 + n * 4;
        const float* We = W_emb + (n * 4) * 32 + f;
        float v = b_emb[n * 32 + f];
        v = fmaf(Xs[0], We[0],  v);
        v = fmaf(Xs[1], We[32], v);
        v = fmaf(Xs[2], We[64], v);
        v = fmaf(Xs[3], We[96], v);
        lds[s * SSTRIDE + OFF_H + n * 36 + f] = fmaxf(v, 0.f);
    }
    __syncthreads();

    float* pacc = lds + OFF_PACC;

    for (int i = 0; i < 3; i++) {
        if (tid < 11) pacc[tid] = 0.f;
        // conv1
        conv_T(lds, nsamp, w, lane, OFF_H, W_pre1 + i * 68 * 32, b_pre1 + i * 32);
        __syncthreads();
        conv_combine(lds, nsamp, w, lane, W_pre1 + i * 68 * 32);
        __syncthreads();
        agg_phase(lds, nsamp, tid);
        __syncthreads();
        post1_phase(lds, nsamp, w, lane, W1eff + i * 3 * 8 * 512, b_post1 + i * 32);
        __syncthreads();
        // conv2
        conv_T(lds, nsamp, w, lane, OFF_H1, W_pre2 + i * 68 * 32, b_pre2 + i * 32);
        __syncthreads();
        conv_combine(lds, nsamp, w, lane, W_pre2 + i * 68 * 32);
        __syncthreads();
        agg_phase(lds, nsamp, tid);
        __syncthreads();
        post2_partial(lds, nsamp, w, lane, W2eff + i * 384);
        __syncthreads();
        // reduce partials (wave 0), sigmoid, accumulate
        if (w == 0 && lane < nsamp * 11) {
            const int n = lane % 11;
            float h2 = b_post2[i];
#pragma unroll
            for (int ww = 0; ww < 8; ww++) h2 += lds[OFF_PP + ww * 55 + lane];
            const float p = 1.f / (1.f + expf(-h2));
            atomicAdd(pacc + n, p);
        }
        __syncthreads();
        if (tid < 11) atomicAdd(gacc + i * 11 + tid, pacc[tid]);
        __syncthreads();
    }
}

extern "C" __global__ void pna_final(const float* __restrict__ gacc,
                                     const float* __restrict__ W_fc,
                                     const float* __restrict__ b_fc,
                                     float* __restrict__ out)
{
    const int i = threadIdx.x;
    if (i < 3) {
        float acc = 0.f;
        for (int n = 0; n < 11; n++)
            acc = fmaf(gacc[i * 11 + n] * (1.f / 16384.f), W_fc[i * 11 + n], acc);
        out[i] = acc + b_fc[i];
    }
}

extern "C" void kernel_launch(void* const* d_in, const int* in_sizes, int n_in,
                              void* d_out, int out_size, void* d_ws, size_t ws_size,
                              hipStream_t stream)
{
    (void)in_sizes; (void)n_in; (void)out_size; (void)ws_size;
    const float* x_input   = (const float*)d_in[0];
    const float* edge_attr = (const float*)d_in[1];
    const float* W_emb     = (const float*)d_in[2];
    const float* b_emb     = (const float*)d_in[3];
    const float* W_pre1    = (const float*)d_in[4];
    const float* b_pre1    = (const float*)d_in[5];
    const float* W_post1   = (const float*)d_in[6];
    const float* b_post1   = (const float*)d_in[7];
    const float* W_pre2    = (const float*)d_in[8];
    const float* b_pre2    = (const float*)d_in[9];
    const float* W_post2   = (const float*)d_in[10];
    const float* b_post2   = (const float*)d_in[11];
    const float* W_fc      = (const float*)d_in[12];
    const float* b_fc      = (const float*)d_in[13];
    float* ws   = (float*)d_ws;
    float* gacc = ws;                         // [0..32]
    float* out  = (float*)d_out;

    // fold amp/att into per-degree-class post weights; also zeroes gacc
    hipLaunchKernelGGL(pna_fold, dim3(80), dim3(512), 0, stream, W_post1, W_post2, ws);
    const int grid = (B_TOT + SB - 1) / SB;
    const size_t shmem = (size_t)LDS_FLOATS * sizeof(float);
    hipLaunchKernelGGL(pna_main, dim3(grid), dim3(TPB), shmem, stream,
                       x_input, edge_attr, W_emb, b_emb,
                       W_pre1, b_pre1, ws + WS_W1, b_post1,
                       W_pre2, b_pre2, ws + WS_W2, b_post2, gacc);
    hipLaunchKernelGGL(pna_final, dim3(1), dim3(64), 0, stream, gacc, W_fc, b_fc, out);
}

// Round 2
// 374.957 us; speedup vs baseline: 1.8461x; 1.8461x over previous
//
#include <hip/hip_runtime.h>
#include <math.h>

#define B_TOT   16384
#define SB      5
#define TPB     512

// ---- per-sample LDS layout (floats). SSTRIDE%32==12 keeps conv-phase banks spread.
#define SSTRIDE 1868
#define OFF_H   0              // 11*36 = 396
#define OFF_EA  396            // 68
#define OFF_M   464            // 17*36 = 612
#define OFF_H1  OFF_M          // H1 aliases M (disjoint lifetimes)
#define OFF_AGG 1076           // reduced agg: 6*100 (c1) + [600..632) node4 + [640..768) node10
#define OFF_TD  OFF_AGG        // TD/TS alias AGG region (792)
#define OFF_TS  (OFF_AGG + 396)
#define OFF_A4  600            // node4 agg offset within AGG
#define OFF_A10 640            // node10 agg offset within AGG
#define WLDS    (SB * SSTRIDE) // 9340

// ---- folded-weight table layout (same order in ws and in LDS-staged prefix)
#define L_WC1  0               // class1 post1: 96 rows x 32 f ([mean+2mx | mn-mx | std] folds, A2)
#define L_W10  3072            // node10 post1 rows 0..95 ([mean|mn|mx] folds, A4)
#define L_B4   6144            // node4 bias incl sigma0*std-colsum (A1)     (32)
#define L_H1C  6176            // const h1 row for nodes 0..2                (32)
#define L_V1C1 6208            // class1 post2 vector (96)
#define L_V10  6304            // node10 post2 vector (128)
#define L_V4   6432            // node4 post2 vector (32)
#define L_C42  6464            // node4 post2 sigma0 const (1) + 3 pad
#define LTAB   6468            // floats staged to LDS (16B-divisible)
#define G_W10B 6468            // node10 post1 std rows 96..127 (1024) - global only
#define G_W4   7492            // node4 post1 32x32 fold (1024) - global only
#define WTAB   8520            // per-intervention table size (float4-divisible)
#define WS_TAB 64              // ws: [0..32] gacc, [40..42] const-node sigmoid, then tables
#define LDS_FLOATS (WLDS + LTAB)   // 15808 floats = 63232 B  (<=64KB/block, 2 blocks/CU)
#define AVG_LOG 0.9976091242438673f

__constant__ int C_ESRC[17] = {0,0,1,1,2,0,3,4,5,6,7,2,8,3,6,9,1};
__constant__ int C_EDST[17] = {3,4,3,5,5,6,6,7,7,8,8,9,9,10,10,10,10};
__constant__ int C1EA[6] = {0,3,5,7,9,11};     // first in-edge of deg-2 nodes
__constant__ int C1EB[6] = {2,4,6,8,10,12};    // second in-edge
__constant__ int C1N[6]  = {3,5,6,7,8,9};      // deg-2 node ids
__constant__ int CC1[8]  = {0,0,1,2,3,4,5,0};  // (node-3) -> c1 index (deg-2 only)

#define FMA16(a, wb, u) do { \
    float4 w0_ = *(const float4*)(wb); \
    float4 w1_ = *(const float4*)((wb) + 32); \
    float4 w2_ = *(const float4*)((wb) + 64); \
    float4 w3_ = *(const float4*)((wb) + 96); \
    u.x = fmaf(a.x, w0_.x, u.x); u.y = fmaf(a.x, w0_.y, u.y); u.z = fmaf(a.x, w0_.z, u.z); u.w = fmaf(a.x, w0_.w, u.w); \
    u.x = fmaf(a.y, w1_.x, u.x); u.y = fmaf(a.y, w1_.y, u.y); u.z = fmaf(a.y, w1_.z, u.z); u.w = fmaf(a.y, w1_.w, u.w); \
    u.x = fmaf(a.z, w2_.x, u.x); u.y = fmaf(a.z, w2_.y, u.y); u.z = fmaf(a.z, w2_.z, u.z); u.w = fmaf(a.z, w2_.w, u.w); \
    u.x = fmaf(a.w, w3_.x, u.x); u.y = fmaf(a.w, w3_.y, u.y); u.z = fmaf(a.w, w3_.z, u.z); u.w = fmaf(a.w, w3_.w, u.w); \
} while (0)

static __device__ __forceinline__ float coef3(const float* __restrict__ W1, int r, int f, float amp, float att)
{
    return W1[r * 32 + f] + amp * W1[(128 + r) * 32 + f] + att * W1[(256 + r) * 32 + f];
}
static __device__ __forceinline__ float coef3s(const float* __restrict__ W2, int r, float amp, float att)
{
    return W2[r] + amp * W2[128 + r] + att * W2[256 + r];
}

// ---- one-shot fold: amp/att per degree class + graph-structure identities
extern "C" __global__ void pna_fold(const float* __restrict__ W_post1, const float* __restrict__ b_post1,
                                    const float* __restrict__ W_post2, const float* __restrict__ b_post2,
                                    float* __restrict__ ws)
{
    const int t0 = blockIdx.x * blockDim.x + threadIdx.x;
    const int NT = gridDim.x * blockDim.x;
    const float l1 = log1pf(1.f), l2 = log1pf(2.f), l4 = log1pf(4.f);
    const float amp1 = l1 / AVG_LOG, att1 = AVG_LOG / l1;
    const float amp2 = l2 / AVG_LOG, att2 = AVG_LOG / l2;
    const float amp4 = l4 / AVG_LOG, att4 = AVG_LOG / l4;
    const float SIG0 = 0.0031622776601683794f;   // sqrt(1e-5)

    for (int idx = t0; idx < 3 * WTAB; idx += NT) {
        const int i = idx / WTAB, off = idx % WTAB;
        const float* W1 = W_post1 + i * 384 * 32;
        const float* W2 = W_post2 + i * 384;
        float val = 0.f;
        if (off < 3072) {                                   // class1 post1 (deg-2): mx = 2*mean - mn folded
            const int j = off >> 5, f = off & 31, sub = j >> 5, jj = j & 31;
            if (sub == 0)      val = coef3(W1, jj, f, amp2, att2) + 2.f * coef3(W1, 64 + jj, f, amp2, att2);
            else if (sub == 1) val = coef3(W1, 32 + jj, f, amp2, att2) - coef3(W1, 64 + jj, f, amp2, att2);
            else               val = coef3(W1, 96 + jj, f, amp2, att2);
        } else if (off < 6144) {                            // node10 post1 rows 0..95
            const int rr = off - 3072;
            val = coef3(W1, rr >> 5, rr & 31, amp4, att4);
        } else if (off < 6176) {                            // node4 bias (+ sigma0 * std colsum)
            const int f = off - 6144;
            float sum = 0.f;
            for (int jj = 0; jj < 32; ++jj) sum += coef3(W1, 96 + jj, f, amp1, att1);
            val = b_post1[i * 32 + f] + SIG0 * sum;
        } else if (off < 6208) {                            // const h1 row for nodes 0..2
            const int f = off - 6176;
            float sum = 0.f;
            for (int jj = 0; jj < 32; ++jj) sum += coef3(W1, 96 + jj, f, amp1, att1);
            val = fmaxf(b_post1[i * 32 + f] + SIG0 * sum, 0.f);
        } else if (off < 6304) {                            // class1 post2 vector
            const int j = off - 6208, sub = j >> 5, jj = j & 31;
            if (sub == 0)      val = coef3s(W2, jj, amp2, att2) + 2.f * coef3s(W2, 64 + jj, amp2, att2);
            else if (sub == 1) val = coef3s(W2, 32 + jj, amp2, att2) - coef3s(W2, 64 + jj, amp2, att2);
            else               val = coef3s(W2, 96 + jj, amp2, att2);
        } else if (off < 6432) {                            // node10 post2 vector
            val = coef3s(W2, off - 6304, amp4, att4);
        } else if (off < 6464) {                            // node4 post2 vector
            const int jj = off - 6432;
            val = coef3s(W2, jj, amp1, att1) + coef3s(W2, 32 + jj, amp1, att1) + coef3s(W2, 64 + jj, amp1, att1);
        } else if (off == 6464) {                           // node4 post2 sigma0 const
            float sum = 0.f;
            for (int jj = 0; jj < 32; ++jj) sum += coef3s(W2, 96 + jj, amp1, att1);
            val = SIG0 * sum;
        } else if (off >= G_W10B && off < G_W4) {           // node10 post1 std rows 96..127
            const int rr = off - G_W10B;
            val = coef3(W1, 96 + (rr >> 5), rr & 31, amp4, att4);
        } else if (off >= G_W4 && off < 8516) {             // node4 post1: Wm+Wmn+Wmx fold
            const int rr = off - G_W4;
            const int jj = rr >> 5, f = rr & 31;
            val = coef3(W1, jj, f, amp1, att1) + coef3(W1, 32 + jj, f, amp1, att1) + coef3(W1, 64 + jj, f, amp1, att1);
        }
        ws[WS_TAB + idx] = val;
    }
    if (t0 < 40) ws[t0] = 0.f;                              // gacc zero
    if (t0 >= 40 && t0 < 43) {                              // const-node sigmoid (nodes 0..2, per intervention)
        const int i = t0 - 40;
        const float* W2 = W_post2 + i * 384;
        float sum = 0.f;
        for (int jj = 0; jj < 32; ++jj) sum += coef3s(W2, 96 + jj, amp1, att1);
        ws[40 + i] = 1.f / (1.f + expf(-(b_post2[i] + SIG0 * sum)));
    }
}

// ---- per-node transform (unchanged): T[n][f-octet] = H[n] @ Wpre[ty-part] (+bias for dst part)
static __device__ __forceinline__ void conv_T(float* lds, int nsamp, int w, int lane, int hoff,
                                              const float* __restrict__ Wp,
                                              const float* __restrict__ bp)
{
    const int ty = w & 1;
    const int f0 = (w >> 1) * 8;
    const bool act = lane < nsamp * 11;
    const int cidx = act ? lane : 0;
    const int s = cidx / 11, n = cidx % 11;
    const float* Hrow = lds + s * SSTRIDE + hoff + n * 36;
    const float* wbase = Wp + ty * 32 * 32 + f0;        // wave-uniform -> s_load
    float acc[8];
#pragma unroll
    for (int f = 0; f < 8; f++) acc[f] = ty ? 0.f : bp[f0 + f];
#pragma unroll
    for (int kq = 0; kq < 8; kq++) {
        float4 a = *(const float4*)(Hrow + kq * 4);
#pragma unroll
        for (int kk = 0; kk < 4; kk++) {
            float av = (kk == 0) ? a.x : (kk == 1) ? a.y : (kk == 2) ? a.z : a.w;
            const float* wr = wbase + (kq * 4 + kk) * 32;
#pragma unroll
            for (int f = 0; f < 8; f++) acc[f] = fmaf(av, wr[f], acc[f]);
        }
    }
    float* T = lds + s * SSTRIDE + (ty ? OFF_TS : OFF_TD) + n * 36 + f0;
    if (act) {
        *(float4*)(T + 0) = make_float4(acc[0], acc[1], acc[2], acc[3]);
        *(float4*)(T + 4) = make_float4(acc[4], acc[5], acc[6], acc[7]);
    }
}

// ---- combine (unchanged): m[e][f-octet] = relu(Td[dst] + Ts[src] + ea @ Wpre[64:68])
static __device__ __forceinline__ void conv_combine(float* lds, int nsamp, int w, int lane,
                                                    const float* __restrict__ Wp)
{
    const int f0 = (w & 3) * 8, v = w >> 2;
    const int idx = v * 64 + lane;
    const bool act = idx < nsamp * 17;
    const int cidx = act ? idx : 0;
    const int s = cidx / 17, e = cidx % 17;
    float* S = lds + s * SSTRIDE;
    const int nd = C_EDST[e], ns = C_ESRC[e];
    float4 ev = *(const float4*)(S + OFF_EA + e * 4);
    const float* TD = S + OFF_TD + nd * 36 + f0;
    const float* TS = S + OFF_TS + ns * 36 + f0;
    float acc[8];
#pragma unroll
    for (int fq = 0; fq < 2; fq++) {
        float4 td = *(const float4*)(TD + fq * 4);
        float4 ts = *(const float4*)(TS + fq * 4);
        acc[fq*4+0] = td.x + ts.x; acc[fq*4+1] = td.y + ts.y;
        acc[fq*4+2] = td.z + ts.z; acc[fq*4+3] = td.w + ts.w;
    }
    const float* w64 = Wp + 64 * 32 + f0;
    const float* w65 = Wp + 65 * 32 + f0;
    const float* w66 = Wp + 66 * 32 + f0;
    const float* w67 = Wp + 67 * 32 + f0;
#pragma unroll
    for (int f = 0; f < 8; f++) {
        float a = acc[f];
        a = fmaf(ev.x, w64[f], a);
        a = fmaf(ev.y, w65[f], a);
        a = fmaf(ev.z, w66[f], a);
        a = fmaf(ev.w, w67[f], a);
        acc[f] = fmaxf(a, 0.f);
    }
    float* M = S + OFF_M + e * 36 + f0;
    if (act) {
        *(float4*)(M + 0) = make_float4(acc[0], acc[1], acc[2], acc[3]);
        *(float4*)(M + 4) = make_float4(acc[4], acc[5], acc[6], acc[7]);
    }
}

// ---- reduced PNA aggregation: deg-2 -> [mean|mn|std]@c1*100, node4 -> m copy, node10 -> full 128
static __device__ __forceinline__ void agg_new(float* lds, int nsamp, int tid)
{
    if (tid >= nsamp * 64) return;
    const int s = tid >> 6, r = tid & 63;
    float* S = lds + s * SSTRIDE;
    const int q = r & 7, f = q * 4;
    if (r < 48) {
        const int c1 = r >> 3;
        float4 a = *(const float4*)(S + OFF_M + C1EA[c1] * 36 + f);
        float4 b = *(const float4*)(S + OFF_M + C1EB[c1] * 36 + f);
        float4 mean, mn, sd;
        mean.x = (a.x + b.x) * 0.5f; mean.y = (a.y + b.y) * 0.5f;
        mean.z = (a.z + b.z) * 0.5f; mean.w = (a.w + b.w) * 0.5f;
        mn.x = fminf(a.x, b.x); mn.y = fminf(a.y, b.y); mn.z = fminf(a.z, b.z); mn.w = fminf(a.w, b.w);
        float4 msq;
        msq.x = fmaf(b.x, b.x, a.x * a.x) * 0.5f;
        msq.y = fmaf(b.y, b.y, a.y * a.y) * 0.5f;
        msq.z = fmaf(b.z, b.z, a.z * a.z) * 0.5f;
        msq.w = fmaf(b.w, b.w, a.w * a.w) * 0.5f;
        sd.x = sqrtf(fmaxf(msq.x - mean.x * mean.x, 0.f) + 1e-5f);
        sd.y = sqrtf(fmaxf(msq.y - mean.y * mean.y, 0.f) + 1e-5f);
        sd.z = sqrtf(fmaxf(msq.z - mean.z * mean.z, 0.f) + 1e-5f);
        sd.w = sqrtf(fmaxf(msq.w - mean.w * mean.w, 0.f) + 1e-5f);
        float* A = S + OFF_AGG + c1 * 100;
        *(float4*)(A + f) = mean;
        *(float4*)(A + 32 + f) = mn;
        *(float4*)(A + 64 + f) = sd;
    } else if (r < 56) {
        *(float4*)(S + OFF_AGG + OFF_A4 + f) = *(const float4*)(S + OFF_M + 36 + f);   // node4: edge 1
    } else {
        float4 sum = make_float4(0.f,0.f,0.f,0.f), sq = make_float4(0.f,0.f,0.f,0.f);
        float4 mn = make_float4(1e30f,1e30f,1e30f,1e30f), mx = make_float4(-1e30f,-1e30f,-1e30f,-1e30f);
#pragma unroll
        for (int e = 13; e <= 16; e++) {
            float4 mv = *(const float4*)(S + OFF_M + e * 36 + f);
            sum.x += mv.x; sum.y += mv.y; sum.z += mv.z; sum.w += mv.w;
            sq.x = fmaf(mv.x, mv.x, sq.x); sq.y = fmaf(mv.y, mv.y, sq.y);
            sq.z = fmaf(mv.z, mv.z, sq.z); sq.w = fmaf(mv.w, mv.w, sq.w);
            mn.x = fminf(mn.x, mv.x); mn.y = fminf(mn.y, mv.y); mn.z = fminf(mn.z, mv.z); mn.w = fminf(mn.w, mv.w);
            mx.x = fmaxf(mx.x, mv.x); mx.y = fmaxf(mx.y, mv.y); mx.z = fmaxf(mx.z, mv.z); mx.w = fmaxf(mx.w, mv.w);
        }
        float4 mean = make_float4(sum.x*0.25f, sum.y*0.25f, sum.z*0.25f, sum.w*0.25f);
        float4 msq  = make_float4(sq.x*0.25f,  sq.y*0.25f,  sq.z*0.25f,  sq.w*0.25f);
        float4 sd;
        sd.x = sqrtf(fmaxf(msq.x - mean.x*mean.x, 0.f) + 1e-5f);
        sd.y = sqrtf(fmaxf(msq.y - mean.y*mean.y, 0.f) + 1e-5f);
        sd.z = sqrtf(fmaxf(msq.z - mean.z*mean.z, 0.f) + 1e-5f);
        sd.w = sqrtf(fmaxf(msq.w - mean.w*mean.w, 0.f) + 1e-5f);
        float* A = S + OFF_AGG + OFF_A10;
        *(float4*)(A + f) = mean;
        *(float4*)(A + 32 + f) = mn;
        *(float4*)(A + 64 + f) = mx;
        *(float4*)(A + 96 + f) = sd;
    }
}

// ---- post1: type-sorted waves, LDS-resident folded weights
static __device__ __forceinline__ void post1_new(float* lds, const float* wl, int nsamp, int w, int lane,
                                                 const float* __restrict__ bp,      // b_post1 + i*32
                                                 const float* __restrict__ tabg)    // ws table for intervention i
{
    if (w < 4) {
        const int t = w * 60 + lane;
        if (lane < 60 && t < nsamp * 48) {
            const int row = t >> 3, q = t & 7;
            const int s = row / 6, c1 = row - s * 6;
            const float* A = lds + s * SSTRIDE + OFF_AGG + c1 * 100;
            const float* W = wl + L_WC1 + q * 4;
            float4 u = make_float4(0.f,0.f,0.f,0.f);
#pragma unroll 4
            for (int jq = 0; jq < 24; ++jq) {
                float4 a = *(const float4*)(A + jq * 4);
                const float* wb = W + jq * 128;
                FMA16(a, wb, u);
            }
            float4 o;
            o.x = fmaxf(u.x + bp[q*4+0], 0.f);
            o.y = fmaxf(u.y + bp[q*4+1], 0.f);
            o.z = fmaxf(u.z + bp[q*4+2], 0.f);
            o.w = fmaxf(u.w + bp[q*4+3], 0.f);
            *(float4*)(lds + s * SSTRIDE + OFF_H1 + C1N[c1] * 36 + q * 4) = o;
        }
    } else if (w == 4) {
        if (lane < nsamp * 8) {
            const int s = lane >> 3, q = lane & 7;
            const float* A = lds + s * SSTRIDE + OFF_AGG + OFF_A10;
            const float* W = wl + L_W10 + q * 4;
            float4 u = make_float4(0.f,0.f,0.f,0.f);
#pragma unroll 4
            for (int jq = 0; jq < 24; ++jq) {        // mean|mn|mx from LDS
                float4 a = *(const float4*)(A + jq * 4);
                const float* wb = W + jq * 128;
                FMA16(a, wb, u);
            }
            const float* Wg = tabg + G_W10B + q * 4;
#pragma unroll
            for (int jq = 0; jq < 8; ++jq) {         // std rows from global (L2-hot)
                float4 a = *(const float4*)(A + 96 + jq * 4);
                const float* wb = Wg + jq * 128;
                FMA16(a, wb, u);
            }
            float4 o;
            o.x = fmaxf(u.x + bp[q*4+0], 0.f);
            o.y = fmaxf(u.y + bp[q*4+1], 0.f);
            o.z = fmaxf(u.z + bp[q*4+2], 0.f);
            o.w = fmaxf(u.w + bp[q*4+3], 0.f);
            *(float4*)(lds + s * SSTRIDE + OFF_H1 + 10 * 36 + q * 4) = o;
        }
    } else if (w == 5) {
        if (lane < nsamp * 8) {
            const int s = lane >> 3, q = lane & 7;
            const float* A = lds + s * SSTRIDE + OFF_AGG + OFF_A4;
            const float* Wg = tabg + G_W4 + q * 4;
            float4 u = make_float4(0.f,0.f,0.f,0.f);
#pragma unroll
            for (int jq = 0; jq < 8; ++jq) {
                float4 a = *(const float4*)(A + jq * 4);
                const float* wb = Wg + jq * 128;
                FMA16(a, wb, u);
            }
            float4 b4 = *(const float4*)(wl + L_B4 + q * 4);   // bias incl sigma0 std-term
            float4 o;
            o.x = fmaxf(u.x + b4.x, 0.f);
            o.y = fmaxf(u.y + b4.y, 0.f);
            o.z = fmaxf(u.z + b4.z, 0.f);
            o.w = fmaxf(u.w + b4.w, 0.f);
            *(float4*)(lds + s * SSTRIDE + OFF_H1 + 4 * 36 + q * 4) = o;
        }
        for (int c = lane; c < nsamp * 24; c += 64) {           // const h1 rows for nodes 0..2
            const int s = c / 24, rr = c - s * 24, node = rr >> 3, q2 = rr & 7;
            *(float4*)(lds + s * SSTRIDE + OFF_H1 + node * 36 + q2 * 4) =
                *(const float4*)(wl + L_H1C + q2 * 4);
        }
    }
}

// ---- post2 + sigmoid + reduce, single wave, no extra barriers
static __device__ __forceinline__ void post2_new(float* lds, const float* wl, int nsamp, int w, int lane,
                                                 float b2, float* __restrict__ gacc, int i)
{
    if (w != 0) return;
    float p = 0.f;
    if (lane < nsamp * 8) {
        const int s = lane >> 3, nn = lane & 7;
        const float* S = lds + s * SSTRIDE;
        const float* A; const float* V; int jqn; float extra = 0.f;
        if (nn == 1)      { A = S + OFF_AGG + OFF_A4;  V = wl + L_V4;  jqn = 8;  extra = wl[L_C42]; }
        else if (nn == 7) { A = S + OFF_AGG + OFF_A10; V = wl + L_V10; jqn = 32; }
        else              { A = S + OFF_AGG + CC1[nn] * 100; V = wl + L_V1C1; jqn = 24; }
        float u = 0.f;
        for (int jq = 0; jq < jqn; ++jq) {
            float4 a = *(const float4*)(A + jq * 4);
            float4 v = *(const float4*)(V + jq * 4);
            u = fmaf(a.x, v.x, u); u = fmaf(a.y, v.y, u);
            u = fmaf(a.z, v.z, u); u = fmaf(a.w, v.w, u);
        }
        const float h2 = u + b2 + extra;
        p = 1.f / (1.f + expf(-h2));
    }
    p += __shfl_down(p, 8);
    p += __shfl_down(p, 16);
    p += __shfl_down(p, 32);
    if (lane < 8) atomicAdd(gacc + i * 11 + 3 + lane, p);
}

extern "C" __global__ void __launch_bounds__(TPB, 4)
pna_main(const float* __restrict__ x_input, const float* __restrict__ edge_attr,
         const float* __restrict__ W_emb,  const float* __restrict__ b_emb,
         const float* __restrict__ W_pre1, const float* __restrict__ b_pre1,
         const float* __restrict__ b_post1,
         const float* __restrict__ W_pre2, const float* __restrict__ b_pre2,
         const float* __restrict__ b_post2,
         const float* __restrict__ wstab,  float* __restrict__ gacc)
{
    extern __shared__ float lds[];
    const int tid = threadIdx.x;
    const int w = __builtin_amdgcn_readfirstlane(tid >> 6);
    const int lane = tid & 63;
    const int s0 = blockIdx.x * SB;
    const int nsamp = min(SB, B_TOT - s0);
    float* wl = lds + WLDS;

    for (int t = tid; t < nsamp * 68; t += TPB)
        lds[(t / 68) * SSTRIDE + OFF_EA + (t % 68)] = edge_attr[(size_t)s0 * 68 + t];

    for (int t = tid; t < nsamp * 352; t += TPB) {
        const int s = t / 352, r = t % 352, n = r >> 5, f = r & 31;
        const float* Xs = x_input + (size_t)(s0 + s) * 44 + n * 4;
        const float* We = W_emb + (n * 4) * 32 + f;
        float v = b_emb[n * 32 + f];
        v = fmaf(Xs[0], We[0],  v);
        v = fmaf(Xs[1], We[32], v);
        v = fmaf(Xs[2], We[64], v);
        v = fmaf(Xs[3], We[96], v);
        lds[s * SSTRIDE + OFF_H + n * 36 + f] = fmaxf(v, 0.f);
    }
    __syncthreads();

    for (int i = 0; i < 3; i++) {
        const float* tab = wstab + i * WTAB;
        for (int t = tid; t < LTAB / 4; t += TPB)           // stage folded weights -> LDS
            ((float4*)wl)[t] = ((const float4*)tab)[t];
        conv_T(lds, nsamp, w, lane, OFF_H, W_pre1 + i * 68 * 32, b_pre1 + i * 32);
        __syncthreads();
        conv_combine(lds, nsamp, w, lane, W_pre1 + i * 68 * 32);
        __syncthreads();
        agg_new(lds, nsamp, tid);
        __syncthreads();
        post1_new(lds, wl, nsamp, w, lane, b_post1 + i * 32, tab);
        __syncthreads();
        conv_T(lds, nsamp, w, lane, OFF_H1, W_pre2 + i * 68 * 32, b_pre2 + i * 32);
        __syncthreads();
        conv_combine(lds, nsamp, w, lane, W_pre2 + i * 68 * 32);
        __syncthreads();
        agg_new(lds, nsamp, tid);
        __syncthreads();
        post2_new(lds, wl, nsamp, w, lane, b_post2[i], gacc, i);
        __syncthreads();
    }
}

extern "C" __global__ void pna_final(const float* __restrict__ ws,
                                     const float* __restrict__ W_fc,
                                     const float* __restrict__ b_fc,
                                     float* __restrict__ out)
{
    const int i = threadIdx.x;
    if (i < 3) {
        float acc = 0.f;
        for (int n = 0; n < 11; n++)
            acc = fmaf(ws[i * 11 + n] * (1.f / 16384.f), W_fc[i * 11 + n], acc);
        const float pc = ws[40 + i];
        const float wsum = W_fc[i * 11 + 0] + W_fc[i * 11 + 1] + W_fc[i * 11 + 2];
        out[i] = acc + pc * wsum + b_fc[i];
    }
}

extern "C" void kernel_launch(void* const* d_in, const int* in_sizes, int n_in,
                              void* d_out, int out_size, void* d_ws, size_t ws_size,
                              hipStream_t stream)
{
    (void)in_sizes; (void)n_in; (void)out_size; (void)ws_size;
    const float* x_input   = (const float*)d_in[0];
    const float* edge_attr = (const float*)d_in[1];
    const float* W_emb     = (const float*)d_in[2];
    const float* b_emb     = (const float*)d_in[3];
    const float* W_pre1    = (const float*)d_in[4];
    const float* b_pre1    = (const float*)d_in[5];
    const float* W_post1   = (const float*)d_in[6];
    const float* b_post1   = (const float*)d_in[7];
    const float* W_pre2    = (const float*)d_in[8];
    const float* b_pre2    = (const float*)d_in[9];
    const float* W_post2   = (const float*)d_in[10];
    const float* b_post2   = (const float*)d_in[11];
    const float* W_fc      = (const float*)d_in[12];
    const float* b_fc      = (const float*)d_in[13];
    float* ws  = (float*)d_ws;
    float* out = (float*)d_out;

    hipLaunchKernelGGL(pna_fold, dim3(64), dim3(512), 0, stream,
                       W_post1, b_post1, W_post2, b_post2, ws);
    const int grid = (B_TOT + SB - 1) / SB;
    const size_t shmem = (size_t)LDS_FLOATS * sizeof(float);
    hipLaunchKernelGGL(pna_main, dim3(grid), dim3(TPB), shmem, stream,
                       x_input, edge_attr, W_emb, b_emb,
                       W_pre1, b_pre1, b_post1,
                       W_pre2, b_pre2, b_post2,
                       ws + WS_TAB, ws);
    hipLaunchKernelGGL(pna_final, dim3(1), dim3(64), 0, stream, ws, W_fc, b_fc, out);
}

// Round 3
// 351.483 us; speedup vs baseline: 1.9694x; 1.0668x over previous
//
#include <hip/hip_runtime.h>
#include <math.h>

#define B_TOT   16384
#define SB      5
#define TPB     512

// ---- per-sample LDS layout (floats). SSTRIDE%32==12 keeps conv-phase banks spread.
#define SSTRIDE 1868
#define OFF_H   0              // 11*36 = 396
#define OFF_EA  396            // 68
#define OFF_M   464            // 17*36 = 612
#define OFF_H1  OFF_M          // H1 aliases M (disjoint lifetimes)
#define OFF_AGG 1076           // reduced agg: 6*100 (c1) + [600..632) node4 + [640..768) node10
#define OFF_TD  OFF_AGG        // TD/TS alias AGG region (792)
#define OFF_TS  (OFF_AGG + 396)
#define OFF_A4  600            // node4 agg offset within AGG
#define OFF_A10 640            // node10 agg offset within AGG
#define WLDS    (SB * SSTRIDE) // 9340

// ---- folded-weight table. LDS-staged prefix = only what multiple waves read.
#define L_WC1  0               // class1 post1: 96 rows x 32 f (6 waves read)    (3072)
#define L_B4   3072            // node4 bias incl sigma0*std-colsum              (32)
#define L_H1C  3104            // const h1 row for nodes 0..2                    (32)
#define L_V1C1 3136            // class1 post2 vector                            (96)
#define L_V10  3232            // node10 post2 vector                            (128)
#define L_V4   3360            // node4 post2 vector                             (32)
#define L_C42  3392            // node4 post2 sigma0 const (1) + 3 pad
#define LTAB   3396            // floats staged to LDS (13.6 KB)
#define G_W10  3396            // node10 post1 full 128 rows x 32 (wave6 only, global) (4096)
#define G_W4   7492            // node4 post1 32x32 fold (wave7 only, global)          (1024)
#define WTAB   8520            // per-intervention table stride (16B-divisible)
#define WS_TAB 64              // ws: [0..39] gacc, [40..42] const-node sigmoid, then tables
#define LDS_FLOATS (WLDS + LTAB)   // 12736 floats = 50944 B -> 3 blocks/CU
#define AVG_LOG 0.9976091242438673f

__constant__ int C_ESRC[17] = {0,0,1,1,2,0,3,4,5,6,7,2,8,3,6,9,1};
__constant__ int C_EDST[17] = {3,4,3,5,5,6,6,7,7,8,8,9,9,10,10,10,10};
__constant__ int C1EA[6] = {0,3,5,7,9,11};     // first in-edge of deg-2 nodes
__constant__ int C1EB[6] = {2,4,6,8,10,12};    // second in-edge
__constant__ int C1N[6]  = {3,5,6,7,8,9};      // deg-2 node ids
__constant__ int CC1[8]  = {0,0,1,2,3,4,5,0};  // (node-3) -> c1 index (deg-2 only)

#define FMA16(a, wb, u) do { \
    float4 w0_ = *(const float4*)(wb); \
    float4 w1_ = *(const float4*)((wb) + 32); \
    float4 w2_ = *(const float4*)((wb) + 64); \
    float4 w3_ = *(const float4*)((wb) + 96); \
    u.x = fmaf(a.x, w0_.x, u.x); u.y = fmaf(a.x, w0_.y, u.y); u.z = fmaf(a.x, w0_.z, u.z); u.w = fmaf(a.x, w0_.w, u.w); \
    u.x = fmaf(a.y, w1_.x, u.x); u.y = fmaf(a.y, w1_.y, u.y); u.z = fmaf(a.y, w1_.z, u.z); u.w = fmaf(a.y, w1_.w, u.w); \
    u.x = fmaf(a.z, w2_.x, u.x); u.y = fmaf(a.z, w2_.y, u.y); u.z = fmaf(a.z, w2_.z, u.z); u.w = fmaf(a.z, w2_.w, u.w); \
    u.x = fmaf(a.w, w3_.x, u.x); u.y = fmaf(a.w, w3_.y, u.y); u.z = fmaf(a.w, w3_.z, u.z); u.w = fmaf(a.w, w3_.w, u.w); \
} while (0)

static __device__ __forceinline__ float coef3(const float* __restrict__ W1, int r, int f, float amp, float att)
{
    return W1[r * 32 + f] + amp * W1[(128 + r) * 32 + f] + att * W1[(256 + r) * 32 + f];
}
static __device__ __forceinline__ float coef3s(const float* __restrict__ W2, int r, float amp, float att)
{
    return W2[r] + amp * W2[128 + r] + att * W2[256 + r];
}

// ---- one-shot fold: amp/att per degree class + graph-structure identities
extern "C" __global__ void pna_fold(const float* __restrict__ W_post1, const float* __restrict__ b_post1,
                                    const float* __restrict__ W_post2, const float* __restrict__ b_post2,
                                    float* __restrict__ ws)
{
    const int t0 = blockIdx.x * blockDim.x + threadIdx.x;
    const int NT = gridDim.x * blockDim.x;
    const float l1 = log1pf(1.f), l2 = log1pf(2.f), l4 = log1pf(4.f);
    const float amp1 = l1 / AVG_LOG, att1 = AVG_LOG / l1;
    const float amp2 = l2 / AVG_LOG, att2 = AVG_LOG / l2;
    const float amp4 = l4 / AVG_LOG, att4 = AVG_LOG / l4;
    const float SIG0 = 0.0031622776601683794f;   // sqrt(1e-5)

    for (int idx = t0; idx < 3 * WTAB; idx += NT) {
        const int i = idx / WTAB, off = idx % WTAB;
        const float* W1 = W_post1 + i * 384 * 32;
        const float* W2 = W_post2 + i * 384;
        float val = 0.f;
        if (off < 3072) {                                   // class1 post1 (deg-2): mx = 2*mean - mn folded
            const int j = off >> 5, f = off & 31, sub = j >> 5, jj = j & 31;
            if (sub == 0)      val = coef3(W1, jj, f, amp2, att2) + 2.f * coef3(W1, 64 + jj, f, amp2, att2);
            else if (sub == 1) val = coef3(W1, 32 + jj, f, amp2, att2) - coef3(W1, 64 + jj, f, amp2, att2);
            else               val = coef3(W1, 96 + jj, f, amp2, att2);
        } else if (off < 3104) {                            // node4 bias (+ sigma0 * std colsum)
            const int f = off - 3072;
            float sum = 0.f;
            for (int jj = 0; jj < 32; ++jj) sum += coef3(W1, 96 + jj, f, amp1, att1);
            val = b_post1[i * 32 + f] + SIG0 * sum;
        } else if (off < 3136) {                            // const h1 row for nodes 0..2
            const int f = off - 3104;
            float sum = 0.f;
            for (int jj = 0; jj < 32; ++jj) sum += coef3(W1, 96 + jj, f, amp1, att1);
            val = fmaxf(b_post1[i * 32 + f] + SIG0 * sum, 0.f);
        } else if (off < 3232) {                            // class1 post2 vector
            const int j = off - 3136, sub = j >> 5, jj = j & 31;
            if (sub == 0)      val = coef3s(W2, jj, amp2, att2) + 2.f * coef3s(W2, 64 + jj, amp2, att2);
            else if (sub == 1) val = coef3s(W2, 32 + jj, amp2, att2) - coef3s(W2, 64 + jj, amp2, att2);
            else               val = coef3s(W2, 96 + jj, amp2, att2);
        } else if (off < 3360) {                            // node10 post2 vector
            val = coef3s(W2, off - 3232, amp4, att4);
        } else if (off < 3392) {                            // node4 post2 vector
            const int jj = off - 3360;
            val = coef3s(W2, jj, amp1, att1) + coef3s(W2, 32 + jj, amp1, att1) + coef3s(W2, 64 + jj, amp1, att1);
        } else if (off == 3392) {                           // node4 post2 sigma0 const
            float sum = 0.f;
            for (int jj = 0; jj < 32; ++jj) sum += coef3s(W2, 96 + jj, amp1, att1);
            val = SIG0 * sum;
        } else if (off >= G_W10 && off < G_W4) {            // node10 post1 full 128 rows (global-only)
            const int rr = off - G_W10;
            val = coef3(W1, rr >> 5, rr & 31, amp4, att4);
        } else if (off >= G_W4 && off < G_W4 + 1024) {      // node4 post1: Wm+Wmn+Wmx fold (global-only)
            const int rr = off - G_W4;
            const int jj = rr >> 5, f = rr & 31;
            val = coef3(W1, jj, f, amp1, att1) + coef3(W1, 32 + jj, f, amp1, att1) + coef3(W1, 64 + jj, f, amp1, att1);
        }
        ws[WS_TAB + idx] = val;
    }
    if (t0 < 40) ws[t0] = 0.f;                              // gacc zero
    if (t0 >= 40 && t0 < 43) {                              // const-node sigmoid (nodes 0..2, per intervention)
        const int i = t0 - 40;
        const float* W2 = W_post2 + i * 384;
        float sum = 0.f;
        for (int jj = 0; jj < 32; ++jj) sum += coef3s(W2, 96 + jj, amp1, att1);
        ws[40 + i] = 1.f / (1.f + expf(-(b_post2[i] + SIG0 * sum)));
    }
}

// ---- per-node transform: T[n][f-octet] = H[n] @ Wpre[ty-part] (+bias for dst part)
static __device__ __forceinline__ void conv_T(float* lds, int nsamp, int w, int lane, int hoff,
                                              const float* __restrict__ Wp,
                                              const float* __restrict__ bp)
{
    const int ty = w & 1;
    const int f0 = (w >> 1) * 8;
    const bool act = lane < nsamp * 11;
    const int cidx = act ? lane : 0;
    const int s = cidx / 11, n = cidx % 11;
    const float* Hrow = lds + s * SSTRIDE + hoff + n * 36;
    const float* wbase = Wp + ty * 32 * 32 + f0;        // wave-uniform -> s_load
    float acc[8];
#pragma unroll
    for (int f = 0; f < 8; f++) acc[f] = ty ? 0.f : bp[f0 + f];
#pragma unroll
    for (int kq = 0; kq < 8; kq++) {
        float4 a = *(const float4*)(Hrow + kq * 4);
#pragma unroll
        for (int kk = 0; kk < 4; kk++) {
            float av = (kk == 0) ? a.x : (kk == 1) ? a.y : (kk == 2) ? a.z : a.w;
            const float* wr = wbase + (kq * 4 + kk) * 32;
#pragma unroll
            for (int f = 0; f < 8; f++) acc[f] = fmaf(av, wr[f], acc[f]);
        }
    }
    float* T = lds + s * SSTRIDE + (ty ? OFF_TS : OFF_TD) + n * 36 + f0;
    if (act) {
        *(float4*)(T + 0) = make_float4(acc[0], acc[1], acc[2], acc[3]);
        *(float4*)(T + 4) = make_float4(acc[4], acc[5], acc[6], acc[7]);
    }
}

// ---- combine: m[e][f-octet] = relu(Td[dst] + Ts[src] + ea @ Wpre[64:68])
static __device__ __forceinline__ void conv_combine(float* lds, int nsamp, int w, int lane,
                                                    const float* __restrict__ Wp)
{
    const int f0 = (w & 3) * 8, v = w >> 2;
    const int idx = v * 64 + lane;
    const bool act = idx < nsamp * 17;
    const int cidx = act ? idx : 0;
    const int s = cidx / 17, e = cidx % 17;
    float* S = lds + s * SSTRIDE;
    const int nd = C_EDST[e], ns = C_ESRC[e];
    float4 ev = *(const float4*)(S + OFF_EA + e * 4);
    const float* TD = S + OFF_TD + nd * 36 + f0;
    const float* TS = S + OFF_TS + ns * 36 + f0;
    float acc[8];
#pragma unroll
    for (int fq = 0; fq < 2; fq++) {
        float4 td = *(const float4*)(TD + fq * 4);
        float4 ts = *(const float4*)(TS + fq * 4);
        acc[fq*4+0] = td.x + ts.x; acc[fq*4+1] = td.y + ts.y;
        acc[fq*4+2] = td.z + ts.z; acc[fq*4+3] = td.w + ts.w;
    }
    const float* w64 = Wp + 64 * 32 + f0;
    const float* w65 = Wp + 65 * 32 + f0;
    const float* w66 = Wp + 66 * 32 + f0;
    const float* w67 = Wp + 67 * 32 + f0;
#pragma unroll
    for (int f = 0; f < 8; f++) {
        float a = acc[f];
        a = fmaf(ev.x, w64[f], a);
        a = fmaf(ev.y, w65[f], a);
        a = fmaf(ev.z, w66[f], a);
        a = fmaf(ev.w, w67[f], a);
        acc[f] = fmaxf(a, 0.f);
    }
    float* M = S + OFF_M + e * 36 + f0;
    if (act) {
        *(float4*)(M + 0) = make_float4(acc[0], acc[1], acc[2], acc[3]);
        *(float4*)(M + 4) = make_float4(acc[4], acc[5], acc[6], acc[7]);
    }
}

// ---- reduced PNA aggregation: deg-2 -> [mean|mn|std]@c1*100, node4 -> m copy, node10 -> full 128
static __device__ __forceinline__ void agg_new(float* lds, int nsamp, int tid)
{
    if (tid >= nsamp * 64) return;
    const int s = tid >> 6, r = tid & 63;
    float* S = lds + s * SSTRIDE;
    const int q = r & 7, f = q * 4;
    if (r < 48) {
        const int c1 = r >> 3;
        float4 a = *(const float4*)(S + OFF_M + C1EA[c1] * 36 + f);
        float4 b = *(const float4*)(S + OFF_M + C1EB[c1] * 36 + f);
        float4 mean, mn, sd;
        mean.x = (a.x + b.x) * 0.5f; mean.y = (a.y + b.y) * 0.5f;
        mean.z = (a.z + b.z) * 0.5f; mean.w = (a.w + b.w) * 0.5f;
        mn.x = fminf(a.x, b.x); mn.y = fminf(a.y, b.y); mn.z = fminf(a.z, b.z); mn.w = fminf(a.w, b.w);
        float4 msq;
        msq.x = fmaf(b.x, b.x, a.x * a.x) * 0.5f;
        msq.y = fmaf(b.y, b.y, a.y * a.y) * 0.5f;
        msq.z = fmaf(b.z, b.z, a.z * a.z) * 0.5f;
        msq.w = fmaf(b.w, b.w, a.w * a.w) * 0.5f;
        sd.x = sqrtf(fmaxf(msq.x - mean.x * mean.x, 0.f) + 1e-5f);
        sd.y = sqrtf(fmaxf(msq.y - mean.y * mean.y, 0.f) + 1e-5f);
        sd.z = sqrtf(fmaxf(msq.z - mean.z * mean.z, 0.f) + 1e-5f);
        sd.w = sqrtf(fmaxf(msq.w - mean.w * mean.w, 0.f) + 1e-5f);
        float* A = S + OFF_AGG + c1 * 100;
        *(float4*)(A + f) = mean;
        *(float4*)(A + 32 + f) = mn;
        *(float4*)(A + 64 + f) = sd;
    } else if (r < 56) {
        *(float4*)(S + OFF_AGG + OFF_A4 + f) = *(const float4*)(S + OFF_M + 36 + f);   // node4: edge 1
    } else {
        float4 sum = make_float4(0.f,0.f,0.f,0.f), sq = make_float4(0.f,0.f,0.f,0.f);
        float4 mn = make_float4(1e30f,1e30f,1e30f,1e30f), mx = make_float4(-1e30f,-1e30f,-1e30f,-1e30f);
#pragma unroll
        for (int e = 13; e <= 16; e++) {
            float4 mv = *(const float4*)(S + OFF_M + e * 36 + f);
            sum.x += mv.x; sum.y += mv.y; sum.z += mv.z; sum.w += mv.w;
            sq.x = fmaf(mv.x, mv.x, sq.x); sq.y = fmaf(mv.y, mv.y, sq.y);
            sq.z = fmaf(mv.z, mv.z, sq.z); sq.w = fmaf(mv.w, mv.w, sq.w);
            mn.x = fminf(mn.x, mv.x); mn.y = fminf(mn.y, mv.y); mn.z = fminf(mn.z, mv.z); mn.w = fminf(mn.w, mv.w);
            mx.x = fmaxf(mx.x, mv.x); mx.y = fmaxf(mx.y, mv.y); mx.z = fmaxf(mx.z, mv.z); mx.w = fmaxf(mx.w, mv.w);
        }
        float4 mean = make_float4(sum.x*0.25f, sum.y*0.25f, sum.z*0.25f, sum.w*0.25f);
        float4 msq  = make_float4(sq.x*0.25f,  sq.y*0.25f,  sq.z*0.25f,  sq.w*0.25f);
        float4 sd;
        sd.x = sqrtf(fmaxf(msq.x - mean.x*mean.x, 0.f) + 1e-5f);
        sd.y = sqrtf(fmaxf(msq.y - mean.y*mean.y, 0.f) + 1e-5f);
        sd.z = sqrtf(fmaxf(msq.z - mean.z*mean.z, 0.f) + 1e-5f);
        sd.w = sqrtf(fmaxf(msq.w - mean.w*mean.w, 0.f) + 1e-5f);
        float* A = S + OFF_AGG + OFF_A10;
        *(float4*)(A + f) = mean;
        *(float4*)(A + 32 + f) = mn;
        *(float4*)(A + 64 + f) = mx;
        *(float4*)(A + 96 + f) = sd;
    }
}

// ---- post1: all 8 waves busy. waves 0-5: class1 (40 lanes, 384 FMA);
//      wave 6: node10 (global weights, 512 FMA); wave 7: node4 + const rows.
static __device__ __forceinline__ void post1_new(float* lds, const float* wl, int nsamp, int w, int lane,
                                                 const float* __restrict__ bp,      // b_post1 + i*32
                                                 const float* __restrict__ tabg)    // ws table for intervention i
{
    if (w < 6) {
        const int t = w * 40 + lane;
        if (lane < 40 && t < nsamp * 48) {
            const int row = t >> 3, q = t & 7;
            const int s = row / 6, c1 = row - s * 6;
            const float* A = lds + s * SSTRIDE + OFF_AGG + c1 * 100;
            const float* W = wl + L_WC1 + q * 4;
            float4 u = make_float4(0.f,0.f,0.f,0.f);
#pragma unroll 4
            for (int jq = 0; jq < 24; ++jq) {
                float4 a = *(const float4*)(A + jq * 4);
                const float* wb = W + jq * 128;
                FMA16(a, wb, u);
            }
            float4 o;
            o.x = fmaxf(u.x + bp[q*4+0], 0.f);
            o.y = fmaxf(u.y + bp[q*4+1], 0.f);
            o.z = fmaxf(u.z + bp[q*4+2], 0.f);
            o.w = fmaxf(u.w + bp[q*4+3], 0.f);
            *(float4*)(lds + s * SSTRIDE + OFF_H1 + C1N[c1] * 36 + q * 4) = o;
        }
    } else if (w == 6) {
        if (lane < nsamp * 8) {
            const int s = lane >> 3, q = lane & 7;
            const float* A = lds + s * SSTRIDE + OFF_AGG + OFF_A10;
            const float* Wg = tabg + G_W10 + q * 4;          // global, L1/L2-hot, 1 wave only
            float4 u = make_float4(0.f,0.f,0.f,0.f);
#pragma unroll 4
            for (int jq = 0; jq < 32; ++jq) {
                float4 a = *(const float4*)(A + jq * 4);
                const float* wb = Wg + jq * 128;
                FMA16(a, wb, u);
            }
            float4 o;
            o.x = fmaxf(u.x + bp[q*4+0], 0.f);
            o.y = fmaxf(u.y + bp[q*4+1], 0.f);
            o.z = fmaxf(u.z + bp[q*4+2], 0.f);
            o.w = fmaxf(u.w + bp[q*4+3], 0.f);
            *(float4*)(lds + s * SSTRIDE + OFF_H1 + 10 * 36 + q * 4) = o;
        }
    } else {  // w == 7
        if (lane < nsamp * 8) {
            const int s = lane >> 3, q = lane & 7;
            const float* A = lds + s * SSTRIDE + OFF_AGG + OFF_A4;
            const float* Wg = tabg + G_W4 + q * 4;
            float4 u = make_float4(0.f,0.f,0.f,0.f);
#pragma unroll
            for (int jq = 0; jq < 8; ++jq) {
                float4 a = *(const float4*)(A + jq * 4);
                const float* wb = Wg + jq * 128;
                FMA16(a, wb, u);
            }
            float4 b4 = *(const float4*)(wl + L_B4 + q * 4);   // bias incl sigma0 std-term
            float4 o;
            o.x = fmaxf(u.x + b4.x, 0.f);
            o.y = fmaxf(u.y + b4.y, 0.f);
            o.z = fmaxf(u.z + b4.z, 0.f);
            o.w = fmaxf(u.w + b4.w, 0.f);
            *(float4*)(lds + s * SSTRIDE + OFF_H1 + 4 * 36 + q * 4) = o;
        }
        for (int c = lane; c < nsamp * 24; c += 64) {           // const h1 rows for nodes 0..2
            const int s = c / 24, rr = c - s * 24, node = rr >> 3, q2 = rr & 7;
            *(float4*)(lds + s * SSTRIDE + OFF_H1 + node * 36 + q2 * 4) =
                *(const float4*)(wl + L_H1C + q2 * 4);
        }
    }
}

// ---- post2 + sigmoid + reduce, single wave, no extra barriers
static __device__ __forceinline__ void post2_new(float* lds, const float* wl, int nsamp, int w, int lane,
                                                 float b2, float* __restrict__ gacc, int i)
{
    if (w != 0) return;
    float p = 0.f;
    if (lane < nsamp * 8) {
        const int s = lane >> 3, nn = lane & 7;
        const float* S = lds + s * SSTRIDE;
        const float* A; const float* V; int jqn; float extra = 0.f;
        if (nn == 1)      { A = S + OFF_AGG + OFF_A4;  V = wl + L_V4;  jqn = 8;  extra = wl[L_C42]; }
        else if (nn == 7) { A = S + OFF_AGG + OFF_A10; V = wl + L_V10; jqn = 32; }
        else              { A = S + OFF_AGG + CC1[nn] * 100; V = wl + L_V1C1; jqn = 24; }
        float u = 0.f;
        for (int jq = 0; jq < jqn; ++jq) {
            float4 a = *(const float4*)(A + jq * 4);
            float4 v = *(const float4*)(V + jq * 4);
            u = fmaf(a.x, v.x, u); u = fmaf(a.y, v.y, u);
            u = fmaf(a.z, v.z, u); u = fmaf(a.w, v.w, u);
        }
        const float h2 = u + b2 + extra;
        p = 1.f / (1.f + expf(-h2));
    }
    p += __shfl_down(p, 8);
    p += __shfl_down(p, 16);
    p += __shfl_down(p, 32);
    if (lane < 8) atomicAdd(gacc + i * 11 + 3 + lane, p);
}

extern "C" __global__ void __launch_bounds__(TPB, 6)
pna_main(const float* __restrict__ x_input, const float* __restrict__ edge_attr,
         const float* __restrict__ W_emb,  const float* __restrict__ b_emb,
         const float* __restrict__ W_pre1, const float* __restrict__ b_pre1,
         const float* __restrict__ b_post1,
         const float* __restrict__ W_pre2, const float* __restrict__ b_pre2,
         const float* __restrict__ b_post2,
         const float* __restrict__ wstab,  float* __restrict__ gacc)
{
    extern __shared__ float lds[];
    const int tid = threadIdx.x;
    const int w = __builtin_amdgcn_readfirstlane(tid >> 6);
    const int lane = tid & 63;
    const int s0 = blockIdx.x * SB;
    const int nsamp = min(SB, B_TOT - s0);
    float* wl = lds + WLDS;

    for (int t = tid; t < nsamp * 68; t += TPB)
        lds[(t / 68) * SSTRIDE + OFF_EA + (t % 68)] = edge_attr[(size_t)s0 * 68 + t];

    for (int t = tid; t < nsamp * 352; t += TPB) {
        const int s = t / 352, r = t % 352, n = r >> 5, f = r & 31;
        const float* Xs = x_input + (size_t)(s0 + s) * 44 + n * 4;
        const float* We = W_emb + (n * 4) * 32 + f;
        float v = b_emb[n * 32 + f];
        v = fmaf(Xs[0], We[0],  v);
        v = fmaf(Xs[1], We[32], v);
        v = fmaf(Xs[2], We[64], v);
        v = fmaf(Xs[3], We[96], v);
        lds[s * SSTRIDE + OFF_H + n * 36 + f] = fmaxf(v, 0.f);
    }
    __syncthreads();

    for (int i = 0; i < 3; i++) {
        const float* tab = wstab + i * WTAB;
        for (int t = tid; t < LTAB / 4; t += TPB)           // stage hot folded weights -> LDS (13.6 KB)
            ((float4*)wl)[t] = ((const float4*)tab)[t];
        conv_T(lds, nsamp, w, lane, OFF_H, W_pre1 + i * 68 * 32, b_pre1 + i * 32);
        __syncthreads();
        conv_combine(lds, nsamp, w, lane, W_pre1 + i * 68 * 32);
        __syncthreads();
        agg_new(lds, nsamp, tid);
        __syncthreads();
        post1_new(lds, wl, nsamp, w, lane, b_post1 + i * 32, tab);
        __syncthreads();
        conv_T(lds, nsamp, w, lane, OFF_H1, W_pre2 + i * 68 * 32, b_pre2 + i * 32);
        __syncthreads();
        conv_combine(lds, nsamp, w, lane, W_pre2 + i * 68 * 32);
        __syncthreads();
        agg_new(lds, nsamp, tid);
        __syncthreads();
        post2_new(lds, wl, nsamp, w, lane, b_post2[i], gacc, i);
        __syncthreads();
    }
}

extern "C" __global__ void pna_final(const float* __restrict__ ws,
                                     const float* __restrict__ W_fc,
                                     const float* __restrict__ b_fc,
                                     float* __restrict__ out)
{
    const int i = threadIdx.x;
    if (i < 3) {
        float acc = 0.f;
        for (int n = 0; n < 11; n++)
            acc = fmaf(ws[i * 11 + n] * (1.f / 16384.f), W_fc[i * 11 + n], acc);
        const float pc = ws[40 + i];
        const float wsum = W_fc[i * 11 + 0] + W_fc[i * 11 + 1] + W_fc[i * 11 + 2];
        out[i] = acc + pc * wsum + b_fc[i];
    }
}

extern "C" void kernel_launch(void* const* d_in, const int* in_sizes, int n_in,
                              void* d_out, int out_size, void* d_ws, size_t ws_size,
                              hipStream_t stream)
{
    (void)in_sizes; (void)n_in; (void)out_size; (void)ws_size;
    const float* x_input   = (const float*)d_in[0];
    const float* edge_attr = (const float*)d_in[1];
    const float* W_emb     = (const float*)d_in[2];
    const float* b_emb     = (const float*)d_in[3];
    const float* W_pre1    = (const float*)d_in[4];
    const float* b_pre1    = (const float*)d_in[5];
    const float* W_post1   = (const float*)d_in[6];
    const float* b_post1   = (const float*)d_in[7];
    const float* W_pre2    = (const float*)d_in[8];
    const float* b_pre2    = (const float*)d_in[9];
    const float* W_post2   = (const float*)d_in[10];
    const float* b_post2   = (const float*)d_in[11];
    const float* W_fc      = (const float*)d_in[12];
    const float* b_fc      = (const float*)d_in[13];
    float* ws  = (float*)d_ws;
    float* out = (float*)d_out;

    hipLaunchKernelGGL(pna_fold, dim3(64), dim3(512), 0, stream,
                       W_post1, b_post1, W_post2, b_post2, ws);
    const int grid = (B_TOT + SB - 1) / SB;
    const size_t shmem = (size_t)LDS_FLOATS * sizeof(float);
    hipLaunchKernelGGL(pna_main, dim3(grid), dim3(TPB), shmem, stream,
                       x_input, edge_attr, W_emb, b_emb,
                       W_pre1, b_pre1, b_post1,
                       W_pre2, b_pre2, b_post2,
                       ws + WS_TAB, ws);
    hipLaunchKernelGGL(pna_final, dim3(1), dim3(64), 0, stream, ws, W_fc, b_fc, out);
}